// Round 1
// baseline (443.528 us; speedup 1.0000x reference)
//
#include <hip/hip_runtime.h>
#include <hip/hip_bf16.h>
#include <float.h>

// Problem: B=4, S=2048, D=1024 causal attention with input projections.
// out = softmax(mask((q@Wq)(k@Wk)^T / 32)) @ (v@Wv)

typedef __attribute__((ext_vector_type(8))) short bf16x8;
typedef __attribute__((ext_vector_type(4))) short short4v;
typedef __attribute__((ext_vector_type(4))) float f32x4;

#define MFMA16 __builtin_amdgcn_mfma_f32_16x16x32_bf16

__device__ __forceinline__ ushort f2bf(float x) {
  union { float f; unsigned u; } v; v.f = x;
  unsigned r = v.u + 0x7fffu + ((v.u >> 16) & 1u);
  return (ushort)(r >> 16);
}
__device__ __forceinline__ float bf2f(ushort h) {
  union { unsigned u; float f; } v; v.u = ((unsigned)h) << 16;
  return v.f;
}
__device__ __forceinline__ void splitf(float x, ushort& hi, ushort& lo) {
  hi = f2bf(x);
  lo = f2bf(x - bf2f(hi));
}

// ---------------------------------------------------------------------------
// Projection GEMM: O = A(Mx1024) @ W(1024x1024).
// SPLIT=true: bf16x2 (hi/lo) inputs, 3 MFMAs per tile pair, hi/lo bf16 output.
// SPLIT=false: plain bf16, single bf16 output (for v1).
// 128x128 tile, BK=32, 4 waves (2x2), 16x16x32 MFMA, LDS pitch 40.
// ---------------------------------------------------------------------------
template <bool SPLIT>
__global__ __launch_bounds__(256) void proj_kernel(
    const float* __restrict__ A, const float* __restrict__ W,
    ushort* __restrict__ Ohi, ushort* __restrict__ Olo) {
  const int AP = 40;
  __shared__ ushort Ahi[128 * 40], Alo[128 * 40], Bhi[128 * 40], Blo[128 * 40];
  const int tid = threadIdx.x;
  const int lane = tid & 63, w = tid >> 6;
  const int wr = w >> 1, wc = w & 1;
  const int m0 = blockIdx.y * 128, n0 = blockIdx.x * 128;
  const int lr = lane & 15, kg = lane >> 4;
  f32x4 acc[4][4] = {};

  for (int k0 = 0; k0 < 1024; k0 += 32) {
    // Stage A tile (128 rows x 32 cols fp32 -> hi/lo bf16, row-major)
    {
      const int r0 = tid >> 3, f = tid & 7;
#pragma unroll
      for (int p = 0; p < 4; ++p) {
        const int r = r0 + p * 32;
        const float4 x = *reinterpret_cast<const float4*>(
            &A[(size_t)(m0 + r) * 1024 + k0 + f * 4]);
        ushort h[4], l[4];
        splitf(x.x, h[0], l[0]); splitf(x.y, h[1], l[1]);
        splitf(x.z, h[2], l[2]); splitf(x.w, h[3], l[3]);
        *reinterpret_cast<short4v*>(&Ahi[r * AP + f * 4]) =
            short4v{(short)h[0], (short)h[1], (short)h[2], (short)h[3]};
        if (SPLIT)
          *reinterpret_cast<short4v*>(&Alo[r * AP + f * 4]) =
              short4v{(short)l[0], (short)l[1], (short)l[2], (short)l[3]};
      }
    }
    // Stage W tile transposed: Bt[n][k] (n local 0..127, k 0..31)
    {
#pragma unroll
      for (int p = 0; p < 4; ++p) {
        const int lin = tid + p * 256;
        const int kk = lin & 31, j = lin >> 5;
        const float4 x = *reinterpret_cast<const float4*>(
            &W[(size_t)(k0 + kk) * 1024 + n0 + j * 4]);
        const float xs[4] = {x.x, x.y, x.z, x.w};
#pragma unroll
        for (int c = 0; c < 4; ++c) {
          ushort h, l;
          splitf(xs[c], h, l);
          Bhi[(j * 4 + c) * AP + kk] = h;
          if (SPLIT) Blo[(j * 4 + c) * AP + kk] = l;
        }
      }
    }
    __syncthreads();
    bf16x8 ah[4], al[4], bh[4], bl[4];
#pragma unroll
    for (int m = 0; m < 4; ++m) {
      ah[m] = *reinterpret_cast<bf16x8*>(&Ahi[(wr * 64 + m * 16 + lr) * AP + kg * 8]);
      if (SPLIT)
        al[m] = *reinterpret_cast<bf16x8*>(&Alo[(wr * 64 + m * 16 + lr) * AP + kg * 8]);
    }
#pragma unroll
    for (int n = 0; n < 4; ++n) {
      bh[n] = *reinterpret_cast<bf16x8*>(&Bhi[(wc * 64 + n * 16 + lr) * AP + kg * 8]);
      if (SPLIT)
        bl[n] = *reinterpret_cast<bf16x8*>(&Blo[(wc * 64 + n * 16 + lr) * AP + kg * 8]);
    }
#pragma unroll
    for (int m = 0; m < 4; ++m)
#pragma unroll
      for (int n = 0; n < 4; ++n) {
        acc[m][n] = MFMA16(ah[m], bh[n], acc[m][n], 0, 0, 0);
        if (SPLIT) {
          acc[m][n] = MFMA16(ah[m], bl[n], acc[m][n], 0, 0, 0);
          acc[m][n] = MFMA16(al[m], bh[n], acc[m][n], 0, 0, 0);
        }
      }
    __syncthreads();
  }
  // Epilogue: D row = kg*4+reg, col = lr within each 16x16 fragment.
#pragma unroll
  for (int m = 0; m < 4; ++m)
#pragma unroll
    for (int n = 0; n < 4; ++n)
#pragma unroll
      for (int reg = 0; reg < 4; ++reg) {
        const int gm = m0 + wr * 64 + m * 16 + kg * 4 + reg;
        const int gn = n0 + wc * 64 + n * 16 + lr;
        const float xv = acc[m][n][reg];
        if (SPLIT) {
          ushort h, l;
          splitf(xv, h, l);
          Ohi[(size_t)gm * 1024 + gn] = h;
          Olo[(size_t)gm * 1024 + gn] = l;
        } else {
          Ohi[(size_t)gm * 1024 + gn] = f2bf(xv);
        }
      }
}

// ---------------------------------------------------------------------------
// QK^T: scores[b][i][j] = (q1[b,i,:] . k1[b,j,:]) / 32, causal-masked.
// q1/k1 are hi/lo bf16 pairs; bf16x2 product (3 MFMAs). Triangular tile grid.
// ---------------------------------------------------------------------------
__global__ __launch_bounds__(256) void qk_kernel(
    const ushort* __restrict__ q1hi, const ushort* __restrict__ q1lo,
    const ushort* __restrict__ k1hi, const ushort* __restrict__ k1lo,
    float* __restrict__ scores) {
  const int AP = 40;
  __shared__ ushort Ahi[128 * 40], Alo[128 * 40], Bhi[128 * 40], Blo[128 * 40];
  const int tid = threadIdx.x, lane = tid & 63, w = tid >> 6;
  const int wr = w >> 1, wc = w & 1;
  const int b = blockIdx.y;
  // decode triangular index -> (ti, tj), tj <= ti
  int p = blockIdx.x, ti = 0, accp = 0;
  while (accp + ti + 1 <= p) { accp += ti + 1; ++ti; }
  const int tj = p - accp;
  const size_t qbase = (size_t)(b * 2048 + ti * 128);
  const size_t kbase = (size_t)(b * 2048 + tj * 128);
  const int lr = lane & 15, kg = lane >> 4;
  f32x4 acc[4][4] = {};

  for (int k0 = 0; k0 < 1024; k0 += 32) {
    const int r = tid >> 2, f = tid & 3;
#pragma unroll
    for (int pp = 0; pp < 2; ++pp) {
      const int rr = r + pp * 64;
      const size_t ga = (qbase + rr) * 1024 + k0 + f * 8;
      *reinterpret_cast<bf16x8*>(&Ahi[rr * AP + f * 8]) =
          *reinterpret_cast<const bf16x8*>(&q1hi[ga]);
      *reinterpret_cast<bf16x8*>(&Alo[rr * AP + f * 8]) =
          *reinterpret_cast<const bf16x8*>(&q1lo[ga]);
      const size_t gb = (kbase + rr) * 1024 + k0 + f * 8;
      *reinterpret_cast<bf16x8*>(&Bhi[rr * AP + f * 8]) =
          *reinterpret_cast<const bf16x8*>(&k1hi[gb]);
      *reinterpret_cast<bf16x8*>(&Blo[rr * AP + f * 8]) =
          *reinterpret_cast<const bf16x8*>(&k1lo[gb]);
    }
    __syncthreads();
    bf16x8 ah[4], al[4], bh[4], bl[4];
#pragma unroll
    for (int m = 0; m < 4; ++m) {
      ah[m] = *reinterpret_cast<bf16x8*>(&Ahi[(wr * 64 + m * 16 + lr) * AP + kg * 8]);
      al[m] = *reinterpret_cast<bf16x8*>(&Alo[(wr * 64 + m * 16 + lr) * AP + kg * 8]);
    }
#pragma unroll
    for (int n = 0; n < 4; ++n) {
      bh[n] = *reinterpret_cast<bf16x8*>(&Bhi[(wc * 64 + n * 16 + lr) * AP + kg * 8]);
      bl[n] = *reinterpret_cast<bf16x8*>(&Blo[(wc * 64 + n * 16 + lr) * AP + kg * 8]);
    }
#pragma unroll
    for (int m = 0; m < 4; ++m)
#pragma unroll
      for (int n = 0; n < 4; ++n) {
        acc[m][n] = MFMA16(ah[m], bh[n], acc[m][n], 0, 0, 0);
        acc[m][n] = MFMA16(ah[m], bl[n], acc[m][n], 0, 0, 0);
        acc[m][n] = MFMA16(al[m], bh[n], acc[m][n], 0, 0, 0);
      }
    __syncthreads();
  }
  const float sc = 0.03125f;  // 1/sqrt(1024)
#pragma unroll
  for (int m = 0; m < 4; ++m)
#pragma unroll
    for (int n = 0; n < 4; ++n)
#pragma unroll
      for (int reg = 0; reg < 4; ++reg) {
        const int gi = ti * 128 + wr * 64 + m * 16 + kg * 4 + reg;
        const int gj = tj * 128 + wc * 64 + n * 16 + lr;
        float v = acc[m][n][reg] * sc;
        if (gj > gi) v = -FLT_MAX;
        scores[((size_t)b * 2048 + gi) * 2048 + gj] = v;
      }
}

// ---------------------------------------------------------------------------
// Row softmax. One block per row. Writes P as bf16 in-place over the row's own
// fp32 storage (safe: all reads complete before the final barrier).
// P[j] = 0 for j > row (so PV can use full 128-tiles).
// ---------------------------------------------------------------------------
__global__ __launch_bounds__(256) void softmax_kernel(float* __restrict__ scores) {
  __shared__ float red[8];
  const int rb = blockIdx.x;
  const int b = rb >> 11, r = rb & 2047;
  float* srow = scores + ((size_t)(b * 2048 + r)) * 2048;
  ushort* prow = reinterpret_cast<ushort*>(srow);
  const int valid = r + 1;
  const int tid = threadIdx.x, lane = tid & 63, w = tid >> 6;

  float vals[8];
  float mx = -FLT_MAX;
#pragma unroll
  for (int c = 0; c < 8; ++c) {
    const int j = tid + c * 256;
    vals[c] = (j < valid) ? srow[j] : -FLT_MAX;
    mx = fmaxf(mx, vals[c]);
  }
#pragma unroll
  for (int o = 32; o; o >>= 1) mx = fmaxf(mx, __shfl_xor(mx, o));
  if (lane == 0) red[w] = mx;
  __syncthreads();
  mx = fmaxf(fmaxf(red[0], red[1]), fmaxf(red[2], red[3]));

  float ex[8];
  float sum = 0.f;
#pragma unroll
  for (int c = 0; c < 8; ++c) {
    const int j = tid + c * 256;
    ex[c] = (j < valid) ? __expf(vals[c] - mx) : 0.f;
    sum += ex[c];
  }
#pragma unroll
  for (int o = 32; o; o >>= 1) sum += __shfl_xor(sum, o);
  if (lane == 0) red[4 + w] = sum;
  __syncthreads();
  sum = red[4] + red[5] + red[6] + red[7];
  const float inv = 1.f / sum;
#pragma unroll
  for (int c = 0; c < 8; ++c) {
    const int j = tid + c * 256;
    prow[j] = f2bf(ex[c] * inv);
  }
}

// ---------------------------------------------------------------------------
// PV: out[b,i,:] = P[b,i,:] @ v1[b,:,:]. P bf16 rows with pitch 4096 (bf16 view
// of the fp32 scores buffer). Causal: K-loop ends at (ti+1)*128.
// ---------------------------------------------------------------------------
__global__ __launch_bounds__(256) void pv_kernel(
    const float* __restrict__ scores, const ushort* __restrict__ v1,
    float* __restrict__ out) {
  const int AP = 40;
  __shared__ ushort Pa[128 * 40], Vt[128 * 40];
  const int tid = threadIdx.x, lane = tid & 63, w = tid >> 6;
  const int wr = w >> 1, wc = w & 1;
  const int b = blockIdx.z, ti = blockIdx.y, n0 = blockIdx.x * 128;
  const ushort* pbase =
      reinterpret_cast<const ushort*>(scores + (size_t)b * 2048 * 2048);
  const int kend = (ti + 1) * 128;
  const int lr = lane & 15, kg = lane >> 4;
  f32x4 acc[4][4] = {};

  for (int k0 = 0; k0 < kend; k0 += 32) {
    const int r = tid >> 2, f = tid & 3;
#pragma unroll
    for (int pp = 0; pp < 2; ++pp) {
      const int rr = r + pp * 64;
      *reinterpret_cast<bf16x8*>(&Pa[rr * AP + f * 8]) =
          *reinterpret_cast<const bf16x8*>(
              &pbase[(size_t)(ti * 128 + rr) * 4096 + k0 + f * 8]);
    }
#pragma unroll
    for (int pp = 0; pp < 4; ++pp) {
      const int lin = tid + pp * 256;
      const int kk = lin & 31, j = lin >> 5;
      const ushort4 x = *reinterpret_cast<const ushort4*>(
          &v1[(size_t)(b * 2048 + k0 + kk) * 1024 + n0 + j * 4]);
      Vt[(j * 4 + 0) * AP + kk] = x.x;
      Vt[(j * 4 + 1) * AP + kk] = x.y;
      Vt[(j * 4 + 2) * AP + kk] = x.z;
      Vt[(j * 4 + 3) * AP + kk] = x.w;
    }
    __syncthreads();
    bf16x8 pa[4], vb[4];
#pragma unroll
    for (int m = 0; m < 4; ++m)
      pa[m] = *reinterpret_cast<bf16x8*>(&Pa[(wr * 64 + m * 16 + lr) * AP + kg * 8]);
#pragma unroll
    for (int n = 0; n < 4; ++n)
      vb[n] = *reinterpret_cast<bf16x8*>(&Vt[(wc * 64 + n * 16 + lr) * AP + kg * 8]);
#pragma unroll
    for (int m = 0; m < 4; ++m)
#pragma unroll
      for (int n = 0; n < 4; ++n)
        acc[m][n] = MFMA16(pa[m], vb[n], acc[m][n], 0, 0, 0);
    __syncthreads();
  }
#pragma unroll
  for (int m = 0; m < 4; ++m)
#pragma unroll
    for (int n = 0; n < 4; ++n)
#pragma unroll
      for (int reg = 0; reg < 4; ++reg) {
        const int gm = ti * 128 + wr * 64 + m * 16 + kg * 4 + reg;
        const int gn = n0 + wc * 64 + n * 16 + lr;
        out[((size_t)b * 2048 + gm) * 1024 + gn] = acc[m][n][reg];
      }
}

extern "C" void kernel_launch(void* const* d_in, const int* in_sizes, int n_in,
                              void* d_out, int out_size, void* d_ws,
                              size_t ws_size, hipStream_t stream) {
  const float* q = (const float*)d_in[0];
  const float* k = (const float*)d_in[1];
  const float* v = (const float*)d_in[2];
  // d_in[3] = mask (causal, known statically) — ignored.
  const float* Wq = (const float*)d_in[4];
  const float* Wk = (const float*)d_in[5];
  const float* Wv = (const float*)d_in[6];
  float* out = (float*)d_out;

  const size_t MD = (size_t)8192 * 1024;
  ushort* q1hi = (ushort*)d_ws;
  ushort* q1lo = q1hi + MD;
  ushort* k1hi = q1lo + MD;
  ushort* k1lo = k1hi + MD;
  ushort* v1 = k1lo + MD;
  float* scores = (float*)(v1 + MD);
  const size_t need = 5 * MD * 2 + (size_t)4 * 2048 * 2048 * 4;
  if (ws_size < need) return;  // workspace too small — fail visibly

  dim3 blk(256);
  proj_kernel<true><<<dim3(8, 64), blk, 0, stream>>>(q, Wq, q1hi, q1lo);
  proj_kernel<true><<<dim3(8, 64), blk, 0, stream>>>(k, Wk, k1hi, k1lo);
  proj_kernel<false><<<dim3(8, 64), blk, 0, stream>>>(v, Wv, v1, nullptr);
  qk_kernel<<<dim3(136, 4), blk, 0, stream>>>(q1hi, q1lo, k1hi, k1lo, scores);
  softmax_kernel<<<dim3(8192), blk, 0, stream>>>(scores);
  pv_kernel<<<dim3(8, 16, 4), blk, 0, stream>>>(scores, v1, out);
}

// Round 3
// 369.744 us; speedup vs baseline: 1.1996x; 1.1996x over previous
//
#include <hip/hip_runtime.h>
#include <hip/hip_bf16.h>
#include <float.h>

// B=4, S=2048, D=1024 causal attention with input projections.
// out = softmax(mask((q@Wq)(k@Wk)^T / 32)) @ (v@Wv)
//
// Numerics: logits have std ~342 -> q1/k1 and the QK^T product use bf16x2
// (hi/lo) split arithmetic (3 MFMAs), giving ~2^-18 effective precision.
// Splits MUST be round-to-nearest: truncation split (R2) gave 4x the error
// and failed (3.125 > 1.93). v path is plain bf16 (convex combination).

typedef __attribute__((ext_vector_type(8))) short bf16x8;
typedef __attribute__((ext_vector_type(4))) float f32x4;

#define MFMA16 __builtin_amdgcn_mfma_f32_16x16x32_bf16

#if __has_builtin(__builtin_amdgcn_perm)
#define PERM2BF(hi32, lo32) __builtin_amdgcn_perm((hi32), (lo32), 0x07060302u)
#else
#define PERM2BF(hi32, lo32) (((lo32) >> 16) | ((hi32) & 0xffff0000u))
#endif

union U8 { bf16x8 v; unsigned w[4]; };

__device__ __forceinline__ ushort f2bf(float x) {
  union { float f; unsigned u; } v; v.f = x;
  unsigned r = v.u + 0x7fffu + ((v.u >> 16) & 1u);
  return (ushort)(r >> 16);
}
__device__ __forceinline__ float bf2f(ushort h) {
  union { unsigned u; float f; } v; v.u = ((unsigned)h) << 16;
  return v.f;
}
__device__ __forceinline__ void splitf(float x, ushort& hi, ushort& lo) {
  hi = f2bf(x);
  lo = f2bf(x - bf2f(hi));
}
// round-to-nearest-even bf16 as a 32-bit float pattern (low 16 zeroed)
__device__ __forceinline__ unsigned rnbits(unsigned u) {
  return (u + 0x7fffu + ((u >> 16) & 1u)) & 0xffff0000u;
}

// In-register ROUND-TO-NEAREST split of 8 consecutive LDS floats into hi/lo
// bf16x8 fragments. Residual ~2^-18 relative (matches R1's passing numerics).
__device__ __forceinline__ void split8(const float* lp, bf16x8& hi, bf16x8& lo) {
  U8 H, L;
#pragma unroll
  for (int p = 0; p < 4; ++p) {
    const float x0 = lp[2 * p], x1 = lp[2 * p + 1];
    const unsigned r0 = rnbits(__float_as_uint(x0));
    const unsigned r1 = rnbits(__float_as_uint(x1));
    const float d0 = x0 - __uint_as_float(r0);
    const float d1 = x1 - __uint_as_float(r1);
    const unsigned s0 = rnbits(__float_as_uint(d0));
    const unsigned s1 = rnbits(__float_as_uint(d1));
    H.w[p] = PERM2BF(r1, r0);
    L.w[p] = PERM2BF(s1, s0);
  }
  hi = H.v; lo = L.v;
}

// Plain fp32 -> bf16x8 (round-to-nearest) from 8 consecutive LDS floats.
__device__ __forceinline__ bf16x8 cvt8(const float* lp) {
  U8 H;
#pragma unroll
  for (int p = 0; p < 4; ++p) {
    const unsigned u0 = rnbits(__float_as_uint(lp[2 * p]));
    const unsigned u1 = rnbits(__float_as_uint(lp[2 * p + 1]));
    H.w[p] = PERM2BF(u1, u0);
  }
  return H.v;
}

// ---------------------------------------------------------------------------
// global_load_lds staging helpers. LDS layout is linear [128][BK] (no pad —
// required: the LDS dest is wave-uniform base + lane*16B). Chunk = 1024 B.
// ---------------------------------------------------------------------------
#define GLOAD16(gp, lp)                                                        \
  __builtin_amdgcn_global_load_lds(                                            \
      (const __attribute__((address_space(1))) void*)(gp),                     \
      (__attribute__((address_space(3))) void*)(lp), 16, 0, 0)

// bf16 slab 128 x 32 (8 KB, 8 chunks; 16 rows/chunk, 4 lanes/row)
__device__ __forceinline__ void stage_bf16_32(const ushort* g, int pitch,
                                              ushort* lds, int w, int lane) {
#pragma unroll
  for (int i = 0; i < 2; ++i) {
    const int c = w * 2 + i;
    const int row = c * 16 + (lane >> 2);
    const int kp = (lane & 3) * 8;
    GLOAD16(g + (size_t)row * pitch + kp, lds + c * 512);
  }
}
// bf16 slab 128 x 64 (16 KB, 16 chunks; 8 rows/chunk, 8 lanes/row)
__device__ __forceinline__ void stage_bf16_64(const ushort* g, int pitch,
                                              ushort* lds, int w, int lane) {
#pragma unroll
  for (int i = 0; i < 4; ++i) {
    const int c = w * 4 + i;
    const int row = c * 8 + (lane >> 3);
    const int kp = (lane & 7) * 8;
    GLOAD16(g + (size_t)row * pitch + kp, lds + c * 512);
  }
}
// fp32 slab 128 x 32 (16 KB, 16 chunks; 8 rows/chunk, 8 lanes/row)
__device__ __forceinline__ void stage_f32_32(const float* g, int pitch,
                                             float* lds, int w, int lane) {
#pragma unroll
  for (int i = 0; i < 4; ++i) {
    const int c = w * 4 + i;
    const int row = c * 8 + (lane >> 3);
    const int kp = (lane & 7) * 4;
    GLOAD16(g + (size_t)row * pitch + kp, lds + c * 256);
  }
}

// ---------------------------------------------------------------------------
// W transpose + convert: Wt[n][k] = W[k][n] as bf16 hi/lo (or hi only).
// ---------------------------------------------------------------------------
template <bool SPLIT>
__global__ __launch_bounds__(256) void wt_conv(const float* __restrict__ W,
                                               ushort* __restrict__ Th,
                                               ushort* __restrict__ Tl) {
  __shared__ float t[32][33];
  const int bx = blockIdx.x, by = blockIdx.y;  // k-tile, n-tile
  const int r = threadIdx.x >> 3, c4 = (threadIdx.x & 7) * 4;
  const float4 x =
      *reinterpret_cast<const float4*>(&W[(size_t)(bx * 32 + r) * 1024 + by * 32 + c4]);
  t[r][c4] = x.x; t[r][c4 + 1] = x.y; t[r][c4 + 2] = x.z; t[r][c4 + 3] = x.w;
  __syncthreads();
  ushort h[4], l[4];
#pragma unroll
  for (int j = 0; j < 4; ++j) splitf(t[c4 + j][r], h[j], l[j]);
  const size_t o = (size_t)(by * 32 + r) * 1024 + bx * 32 + c4;
  *reinterpret_cast<ushort4*>(&Th[o]) = ushort4{h[0], h[1], h[2], h[3]};
  if (SPLIT)
    *reinterpret_cast<ushort4*>(&Tl[o]) = ushort4{l[0], l[1], l[2], l[3]};
}

// ---------------------------------------------------------------------------
// q/k projection: O = A(8192x1024 fp32) @ Wt^T with bf16x2 split (3 MFMA).
// A staged raw fp32 via global_load_lds, split in-register at frag read.
// Output: hi/lo bf16.
// ---------------------------------------------------------------------------
__global__ __launch_bounds__(256) void proj_qk(
    const float* __restrict__ A, const ushort* __restrict__ Bth,
    const ushort* __restrict__ Btl, ushort* __restrict__ Ohi,
    ushort* __restrict__ Olo) {
  __shared__ float As[128 * 32];
  __shared__ ushort Bhs[128 * 32], Bls[128 * 32];
  const int tid = threadIdx.x, lane = tid & 63, w = tid >> 6;
  const int wr = w >> 1, wc = w & 1;
  const int lr = lane & 15, kg = lane >> 4;
  const int m0 = blockIdx.y * 128, n0 = blockIdx.x * 128;
  f32x4 acc[4][4] = {};

  for (int k0 = 0; k0 < 1024; k0 += 32) {
    stage_f32_32(A + (size_t)m0 * 1024 + k0, 1024, As, w, lane);
    stage_bf16_32(Bth + (size_t)n0 * 1024 + k0, 1024, Bhs, w, lane);
    stage_bf16_32(Btl + (size_t)n0 * 1024 + k0, 1024, Bls, w, lane);
    __syncthreads();
    bf16x8 ah[4], al[4], bh[4], bl[4];
#pragma unroll
    for (int m = 0; m < 4; ++m)
      split8(&As[(wr * 64 + m * 16 + lr) * 32 + kg * 8], ah[m], al[m]);
#pragma unroll
    for (int n = 0; n < 4; ++n) {
      bh[n] = *reinterpret_cast<bf16x8*>(&Bhs[(wc * 64 + n * 16 + lr) * 32 + kg * 8]);
      bl[n] = *reinterpret_cast<bf16x8*>(&Bls[(wc * 64 + n * 16 + lr) * 32 + kg * 8]);
    }
#pragma unroll
    for (int m = 0; m < 4; ++m)
#pragma unroll
      for (int n = 0; n < 4; ++n) {
        acc[m][n] = MFMA16(ah[m], bh[n], acc[m][n], 0, 0, 0);
        acc[m][n] = MFMA16(ah[m], bl[n], acc[m][n], 0, 0, 0);
        acc[m][n] = MFMA16(al[m], bh[n], acc[m][n], 0, 0, 0);
      }
    __syncthreads();
  }
#pragma unroll
  for (int m = 0; m < 4; ++m)
#pragma unroll
    for (int n = 0; n < 4; ++n)
#pragma unroll
      for (int reg = 0; reg < 4; ++reg) {
        const int gm = m0 + wr * 64 + m * 16 + kg * 4 + reg;
        const int gn = n0 + wc * 64 + n * 16 + lr;
        ushort h, l;
        splitf(acc[m][n][reg], h, l);
        Ohi[(size_t)gm * 1024 + gn] = h;
        Olo[(size_t)gm * 1024 + gn] = l;
      }
}

// ---------------------------------------------------------------------------
// v projection, transposed output: v1t[b][d][j] = sum_k Wv[k][d] v[b,j,k].
// A = Wvt bf16 (M = d), B = v fp32 rows (N = global j), both K-contiguous.
// ---------------------------------------------------------------------------
__global__ __launch_bounds__(256) void proj_v(const ushort* __restrict__ Wvt,
                                              const float* __restrict__ V,
                                              ushort* __restrict__ v1t) {
  __shared__ ushort Ahs[128 * 32];
  __shared__ float Bs[128 * 32];
  const int tid = threadIdx.x, lane = tid & 63, w = tid >> 6;
  const int wr = w >> 1, wc = w & 1;
  const int lr = lane & 15, kg = lane >> 4;
  const int m0 = blockIdx.y * 128;   // d-tile
  const int n0 = blockIdx.x * 128;   // global j tile (8192 rows)
  f32x4 acc[4][4] = {};

  for (int k0 = 0; k0 < 1024; k0 += 32) {
    stage_bf16_32(Wvt + (size_t)m0 * 1024 + k0, 1024, Ahs, w, lane);
    stage_f32_32(V + (size_t)n0 * 1024 + k0, 1024, Bs, w, lane);
    __syncthreads();
    bf16x8 ah[4], bh[4];
#pragma unroll
    for (int m = 0; m < 4; ++m)
      ah[m] = *reinterpret_cast<bf16x8*>(&Ahs[(wr * 64 + m * 16 + lr) * 32 + kg * 8]);
#pragma unroll
    for (int n = 0; n < 4; ++n)
      bh[n] = cvt8(&Bs[(wc * 64 + n * 16 + lr) * 32 + kg * 8]);
#pragma unroll
    for (int m = 0; m < 4; ++m)
#pragma unroll
      for (int n = 0; n < 4; ++n)
        acc[m][n] = MFMA16(ah[m], bh[n], acc[m][n], 0, 0, 0);
    __syncthreads();
  }
#pragma unroll
  for (int m = 0; m < 4; ++m)
#pragma unroll
    for (int n = 0; n < 4; ++n)
#pragma unroll
      for (int reg = 0; reg < 4; ++reg) {
        const int gm = m0 + wr * 64 + m * 16 + kg * 4 + reg;  // d
        const int gn = n0 + wc * 64 + n * 16 + lr;            // global j
        const int b = gn >> 11, jj = gn & 2047;
        v1t[((size_t)b << 21) + (size_t)gm * 2048 + jj] = f2bf(acc[m][n][reg]);
      }
}

// ---------------------------------------------------------------------------
// QK^T with bf16x2 split operands (3 MFMA), causal triangular tile grid.
// ---------------------------------------------------------------------------
__global__ __launch_bounds__(256) void qk2(
    const ushort* __restrict__ q1h, const ushort* __restrict__ q1l,
    const ushort* __restrict__ k1h, const ushort* __restrict__ k1l,
    float* __restrict__ scores) {
  __shared__ ushort Ahs[128 * 32], Als[128 * 32], Bhs[128 * 32], Bls[128 * 32];
  const int tid = threadIdx.x, lane = tid & 63, w = tid >> 6;
  const int wr = w >> 1, wc = w & 1;
  const int lr = lane & 15, kg = lane >> 4;
  const int b = blockIdx.y;
  int p = blockIdx.x, ti = 0, accp = 0;
  while (accp + ti + 1 <= p) { accp += ti + 1; ++ti; }
  const int tj = p - accp;
  const size_t qoff = ((size_t)b * 2048 + ti * 128) * 1024;
  const size_t koff = ((size_t)b * 2048 + tj * 128) * 1024;
  f32x4 acc[4][4] = {};

  for (int k0 = 0; k0 < 1024; k0 += 32) {
    stage_bf16_32(q1h + qoff + k0, 1024, Ahs, w, lane);
    stage_bf16_32(q1l + qoff + k0, 1024, Als, w, lane);
    stage_bf16_32(k1h + koff + k0, 1024, Bhs, w, lane);
    stage_bf16_32(k1l + koff + k0, 1024, Bls, w, lane);
    __syncthreads();
    bf16x8 ah[4], al[4], bh[4], bl[4];
#pragma unroll
    for (int m = 0; m < 4; ++m) {
      ah[m] = *reinterpret_cast<bf16x8*>(&Ahs[(wr * 64 + m * 16 + lr) * 32 + kg * 8]);
      al[m] = *reinterpret_cast<bf16x8*>(&Als[(wr * 64 + m * 16 + lr) * 32 + kg * 8]);
    }
#pragma unroll
    for (int n = 0; n < 4; ++n) {
      bh[n] = *reinterpret_cast<bf16x8*>(&Bhs[(wc * 64 + n * 16 + lr) * 32 + kg * 8]);
      bl[n] = *reinterpret_cast<bf16x8*>(&Bls[(wc * 64 + n * 16 + lr) * 32 + kg * 8]);
    }
#pragma unroll
    for (int m = 0; m < 4; ++m)
#pragma unroll
      for (int n = 0; n < 4; ++n) {
        acc[m][n] = MFMA16(ah[m], bh[n], acc[m][n], 0, 0, 0);
        acc[m][n] = MFMA16(ah[m], bl[n], acc[m][n], 0, 0, 0);
        acc[m][n] = MFMA16(al[m], bh[n], acc[m][n], 0, 0, 0);
      }
    __syncthreads();
  }
  const float sc = 0.03125f;  // 1/sqrt(1024)
#pragma unroll
  for (int m = 0; m < 4; ++m)
#pragma unroll
    for (int n = 0; n < 4; ++n)
#pragma unroll
      for (int reg = 0; reg < 4; ++reg) {
        const int gi = ti * 128 + wr * 64 + m * 16 + kg * 4 + reg;
        const int gj = tj * 128 + wc * 64 + n * 16 + lr;
        float v = acc[m][n][reg] * sc;
        if (gj > gi) v = -FLT_MAX;
        scores[((size_t)b * 2048 + gi) * 2048 + gj] = v;
      }
}

// ---------------------------------------------------------------------------
// Row softmax, P written bf16 in place (zeros beyond the causal boundary).
// ---------------------------------------------------------------------------
__global__ __launch_bounds__(256) void softmax_kernel(float* __restrict__ scores) {
  __shared__ float red[8];
  const int rb = blockIdx.x;
  const int b = rb >> 11, r = rb & 2047;
  float* srow = scores + ((size_t)(b * 2048 + r)) * 2048;
  ushort* prow = reinterpret_cast<ushort*>(srow);
  const int valid = r + 1;
  const int tid = threadIdx.x, lane = tid & 63, w = tid >> 6;

  float vals[8];
  float mx = -FLT_MAX;
#pragma unroll
  for (int c = 0; c < 8; ++c) {
    const int j = tid + c * 256;
    vals[c] = (j < valid) ? srow[j] : -FLT_MAX;
    mx = fmaxf(mx, vals[c]);
  }
#pragma unroll
  for (int o = 32; o; o >>= 1) mx = fmaxf(mx, __shfl_xor(mx, o));
  if (lane == 0) red[w] = mx;
  __syncthreads();
  mx = fmaxf(fmaxf(red[0], red[1]), fmaxf(red[2], red[3]));

  float ex[8];
  float sum = 0.f;
#pragma unroll
  for (int c = 0; c < 8; ++c) {
    const int j = tid + c * 256;
    ex[c] = (j < valid) ? __expf(vals[c] - mx) : 0.f;
    sum += ex[c];
  }
#pragma unroll
  for (int o = 32; o; o >>= 1) sum += __shfl_xor(sum, o);
  if (lane == 0) red[4 + w] = sum;
  __syncthreads();
  sum = red[4] + red[5] + red[6] + red[7];
  const float inv = 1.f / sum;
#pragma unroll
  for (int c = 0; c < 8; ++c) {
    const int j = tid + c * 256;
    prow[j] = f2bf(ex[c] * inv);
  }
}

// ---------------------------------------------------------------------------
// PV: out[b,i,:] = P[b,i,:] @ v1. A = P bf16 (pitch 4096), B = v1t (pitch 2048),
// both K-contiguous, BK=64. Causal: K ends at (ti+1)*128.
// ---------------------------------------------------------------------------
__global__ __launch_bounds__(256) void pv2(const float* __restrict__ scores,
                                           const ushort* __restrict__ v1t,
                                           float* __restrict__ out) {
  __shared__ ushort Ps[128 * 64], Vs[128 * 64];
  const int tid = threadIdx.x, lane = tid & 63, w = tid >> 6;
  const int wr = w >> 1, wc = w & 1;
  const int lr = lane & 15, kg = lane >> 4;
  const int b = blockIdx.z;
  const int ti = 15 - blockIdx.y;  // long blocks first
  const int n0 = blockIdx.x * 128;
  const ushort* pbase =
      reinterpret_cast<const ushort*>(scores + (size_t)b * 2048 * 2048) +
      (size_t)(ti * 128) * 4096;
  const ushort* vbase = v1t + ((size_t)b << 21) + (size_t)n0 * 2048;
  const int kend = (ti + 1) * 128;
  f32x4 acc[4][4] = {};

  for (int k0 = 0; k0 < kend; k0 += 64) {
    stage_bf16_64(pbase + k0, 4096, Ps, w, lane);
    stage_bf16_64(vbase + k0, 2048, Vs, w, lane);
    __syncthreads();
#pragma unroll
    for (int t = 0; t < 2; ++t) {
      bf16x8 pa[4], vb[4];
#pragma unroll
      for (int m = 0; m < 4; ++m)
        pa[m] = *reinterpret_cast<bf16x8*>(&Ps[(wr * 64 + m * 16 + lr) * 64 + t * 32 + kg * 8]);
#pragma unroll
      for (int n = 0; n < 4; ++n)
        vb[n] = *reinterpret_cast<bf16x8*>(&Vs[(wc * 64 + n * 16 + lr) * 64 + t * 32 + kg * 8]);
#pragma unroll
      for (int m = 0; m < 4; ++m)
#pragma unroll
        for (int n = 0; n < 4; ++n)
          acc[m][n] = MFMA16(pa[m], vb[n], acc[m][n], 0, 0, 0);
    }
    __syncthreads();
  }
#pragma unroll
  for (int m = 0; m < 4; ++m)
#pragma unroll
    for (int n = 0; n < 4; ++n)
#pragma unroll
      for (int reg = 0; reg < 4; ++reg) {
        const int gm = ti * 128 + wr * 64 + m * 16 + kg * 4 + reg;
        const int gn = n0 + wc * 64 + n * 16 + lr;
        out[((size_t)b * 2048 + gm) * 1024 + gn] = acc[m][n][reg];
      }
}

extern "C" void kernel_launch(void* const* d_in, const int* in_sizes, int n_in,
                              void* d_out, int out_size, void* d_ws,
                              size_t ws_size, hipStream_t stream) {
  const float* q = (const float*)d_in[0];
  const float* k = (const float*)d_in[1];
  const float* v = (const float*)d_in[2];
  // d_in[3] = causal mask — statically known, ignored.
  const float* Wq = (const float*)d_in[4];
  const float* Wk = (const float*)d_in[5];
  const float* Wv = (const float*)d_in[6];
  float* out = (float*)d_out;

  // Workspace layout with liveness aliasing:
  //   [0, 64M)      scores (fp32, 4x2048x2048) — born at qk2.
  //                 The Wt buffers (10 MB) alias its head; dead before qk2.
  //   [64M, 128M)   q1hi q1lo k1hi k1lo (bf16, 4 x 16 MB)
  //   [128M, 144M)  v1t (bf16, 16 MB)
  char* ws = (char*)d_ws;
  float* scores = (float*)ws;
  ushort* Wqth = (ushort*)ws;
  ushort* Wqtl = Wqth + 1048576;
  ushort* Wkth = Wqth + 2 * 1048576;
  ushort* Wktl = Wqth + 3 * 1048576;
  ushort* Wvt  = Wqth + 4 * 1048576;
  ushort* q1hi = (ushort*)(ws + 67108864);
  ushort* q1lo = q1hi + 8388608;
  ushort* k1hi = q1hi + 2 * 8388608;
  ushort* k1lo = q1hi + 3 * 8388608;
  ushort* v1t  = q1hi + 4 * 8388608;
  const size_t need = 67108864 + 5 * 16777216;  // 150,994,944
  if (ws_size < need) return;

  dim3 blk(256);
  wt_conv<true><<<dim3(32, 32), blk, 0, stream>>>(Wq, Wqth, Wqtl);
  wt_conv<true><<<dim3(32, 32), blk, 0, stream>>>(Wk, Wkth, Wktl);
  wt_conv<false><<<dim3(32, 32), blk, 0, stream>>>(Wv, Wvt, nullptr);
  proj_qk<<<dim3(8, 64), blk, 0, stream>>>(q, Wqth, Wqtl, q1hi, q1lo);
  proj_qk<<<dim3(8, 64), blk, 0, stream>>>(k, Wkth, Wktl, k1hi, k1lo);
  proj_v<<<dim3(64, 8), blk, 0, stream>>>(Wvt, v, v1t);
  qk2<<<dim3(136, 4), blk, 0, stream>>>(q1hi, q1lo, k1hi, k1lo, scores);
  softmax_kernel<<<dim3(8192), blk, 0, stream>>>(scores);
  pv2<<<dim3(8, 16, 4), blk, 0, stream>>>(scores, v1t, out);
}